// Round 8
// baseline (154.135 us; speedup 1.0000x reference)
//
#include <hip/hip_runtime.h>

typedef __attribute__((ext_vector_type(8))) _Float16 f16x8;
typedef __attribute__((ext_vector_type(4))) float f32x4;

static constexpr int TT = 100, BB = 256, DD = 784, HH = 256;
static constexpr int MM = TT * BB;      // 25600
static constexpr int K1PAD = 800;       // 784 -> 25*32
static constexpr float MIDSC = 2048.0f, INVMID = 1.0f / 2048.0f;

__device__ __forceinline__ unsigned short f2h(float x) {
  _Float16 h = (_Float16)x;
  return *(unsigned short*)&h;
}
__device__ __forceinline__ float h2f(unsigned short u) {
  _Float16 h = *(_Float16*)&u;
  return (float)h;
}
__device__ __forceinline__ void glds16(const void* g, void* l) {
  __builtin_amdgcn_global_load_lds(
      (const __attribute__((address_space(1))) unsigned int*)g,
      (__attribute__((address_space(3))) unsigned int*)l, 16, 0, 0);
}

// Split fp32 W[N][K] into 2 f16 planes [Npad][Kpad]:
//   p0 = f16(w), p1 = f16((w - p0) * 2048); reconstruct p0 + p1/2048 (~2^-22 rel).
__global__ __launch_bounds__(256)
void split_w(const float* __restrict__ W, unsigned short* __restrict__ Ws,
             int N, int K, int Npad, int Kpad) {
  int idx = blockIdx.x * 256 + threadIdx.x;
  int total = Npad * Kpad;
  if (idx >= total) return;
  int row = idx / Kpad, col = idx - row * Kpad;
  float w = (row < N && col < K) ? W[row * K + col] : 0.0f;
  unsigned short h0 = f2h(w);
  float r = (w - h2f(h0)) * MIDSC;
  Ws[idx] = h0;
  Ws[total + idx] = f2h(r);
}

// Layer-1 GEMM: cur1[M,256] = X[M,784](binary fp32) @ (2-plane f16 W1)^T + b1.
// BM=BN=128, BK=32, 4 waves 2x2, mfma_f32_16x16x32_f16, dual plane accumulators.
// B: glds triple-buffer, counted vmcnt(4) (depth-2, never drained mid-loop).
// A: fp32 binary -> f16 {0,1} packed in regs, ds_written one step ahead (dbuf).
// XOR-swizzled LDS (16B chunks): phys_chunk = log_chunk ^ (((row&15)>>1)&3).
__global__ __launch_bounds__(256, 2)
void gemm1(const float* __restrict__ X, const unsigned short* __restrict__ Bs,
           const float* __restrict__ bias, float* __restrict__ C) {
  constexpr int Kpad = K1PAD, nkb = Kpad / 32;   // 25
  __shared__ unsigned short Asm[2][128 * 32];      // 16 KB
  __shared__ unsigned short Bsm[3][2][128 * 32];   // 48 KB
  const int tid = threadIdx.x;
  const int bm = blockIdx.x * 128, bn = blockIdx.y * 128;
  const int wid = tid >> 6, lane = tid & 63;
  const int wr = (wid >> 1) * 64, wc = (wid & 1) * 64;
  const int l15 = lane & 15, l4 = lane >> 4;

  f32x4 acc[2][4][4];
#pragma unroll
  for (int s = 0; s < 2; ++s)
#pragma unroll
    for (int m = 0; m < 4; ++m)
#pragma unroll
      for (int n = 0; n < 4; ++n) acc[s][m][n] = (f32x4){0.f, 0.f, 0.f, 0.f};

  const int rl = wid * 32 + (lane >> 2);
  const int ce = ((lane & 3) ^ ((lane >> 3) & 3)) * 8;
  const size_t pstr = (size_t)HH * Kpad;
  const unsigned short* bsrc0 = Bs + (size_t)(bn + rl) * Kpad + ce;
  const unsigned short* bsrc1 = Bs + (size_t)(bn + rl + 16) * Kpad + ce;

  const int rdsw = (l4 ^ ((l15 >> 1) & 3)) * 8;

  const int r0 = tid >> 2;
  const int c0log = (tid & 3) * 8;
  const int c0phys = ((tid & 3) ^ ((tid >> 3) & 3)) * 8;

  float4 aA[4], aB[4];

  auto loadA = [&](int kb, float4 (&d)[4]) {
    const int col = kb * 32 + c0log;
    const bool ok = col < DD;
    const int colc = ok ? col : 0;
    const float* p0 = &X[(size_t)(bm + r0) * DD + colc];
    const float* p1 = &X[(size_t)(bm + r0 + 64) * DD + colc];
    d[0] = *(const float4*)p0; d[1] = *(const float4*)(p0 + 4);
    d[2] = *(const float4*)p1; d[3] = *(const float4*)(p1 + 4);
    if (!ok) {
      const float4 z = make_float4(0.f, 0.f, 0.f, 0.f);
      d[0] = z; d[1] = z; d[2] = z; d[3] = z;
    }
  };
  auto packA = [&](int bi, const float4 (&s_)[4]) {
    const unsigned ONE = 0x3C00u;
    auto pk = [&](float a, float b) {
      return (a != 0.f ? ONE : 0u) | (b != 0.f ? (ONE << 16) : 0u);
    };
    uint4 v0, v1;
    v0.x = pk(s_[0].x, s_[0].y); v0.y = pk(s_[0].z, s_[0].w);
    v0.z = pk(s_[1].x, s_[1].y); v0.w = pk(s_[1].z, s_[1].w);
    v1.x = pk(s_[2].x, s_[2].y); v1.y = pk(s_[2].z, s_[2].w);
    v1.z = pk(s_[3].x, s_[3].y); v1.w = pk(s_[3].z, s_[3].w);
    *(uint4*)&Asm[bi][r0 * 32 + c0phys] = v0;
    *(uint4*)&Asm[bi][(r0 + 64) * 32 + c0phys] = v1;
  };
  auto stageB = [&](int t) {
    const int k0 = t * 32, bi = t % 3;
    glds16(bsrc0 + k0, &Bsm[bi][0][(wid * 32) * 32]);
    glds16(bsrc1 + k0, &Bsm[bi][0][(wid * 32 + 16) * 32]);
    glds16(bsrc0 + pstr + k0, &Bsm[bi][1][(wid * 32) * 32]);
    glds16(bsrc1 + pstr + k0, &Bsm[bi][1][(wid * 32 + 16) * 32]);
  };
  auto compute = [&](int kb) {
    const int cb = kb & 1, b3 = kb % 3;
    f16x8 afr[4];
#pragma unroll
    for (int m = 0; m < 4; ++m)
      afr[m] = *(const f16x8*)&Asm[cb][(wr + m * 16 + l15) * 32 + rdsw];
#pragma unroll
    for (int s = 0; s < 2; ++s) {
      f16x8 bfr[4];
#pragma unroll
      for (int n = 0; n < 4; ++n)
        bfr[n] = *(const f16x8*)&Bsm[b3][s][(wc + n * 16 + l15) * 32 + rdsw];
#pragma unroll
      for (int m = 0; m < 4; ++m)
#pragma unroll
        for (int n = 0; n < 4; ++n)
          acc[s][m][n] = __builtin_amdgcn_mfma_f32_16x16x32_f16(afr[m], bfr[n], acc[s][m][n], 0, 0, 0);
    }
  };
  auto stepK = [&](int kb, const float4 (&pk_)[4], float4 (&ld_)[4]) {
    if (kb + 2 < nkb) stageB(kb + 2);
    compute(kb);
    __builtin_amdgcn_sched_barrier(0);
    if (kb + 2 < nkb) asm volatile("s_waitcnt vmcnt(4)" ::: "memory");
    else              asm volatile("s_waitcnt vmcnt(0)" ::: "memory");
    if (kb + 1 < nkb) packA((kb + 1) & 1, pk_);
    if (kb + 2 < nkb) loadA(kb + 2, ld_);
    asm volatile("s_waitcnt lgkmcnt(0)" ::: "memory");
    __builtin_amdgcn_sched_barrier(0);
    __builtin_amdgcn_s_barrier();
    __builtin_amdgcn_sched_barrier(0);
  };

  loadA(0, aA);
  stageB(0); stageB(1);
  asm volatile("s_waitcnt vmcnt(8)" ::: "memory");
  packA(0, aA);
  loadA(1, aB);
  asm volatile("s_waitcnt vmcnt(8)" ::: "memory");
  asm volatile("s_waitcnt lgkmcnt(0)" ::: "memory");
  __builtin_amdgcn_s_barrier();
  __builtin_amdgcn_sched_barrier(0);

  for (int kb2 = 0; kb2 < nkb; kb2 += 2) {
    stepK(kb2, aB, aA);
    if (kb2 + 1 < nkb) stepK(kb2 + 1, aA, aB);
  }

#pragma unroll
  for (int m = 0; m < 4; ++m)
#pragma unroll
    for (int n = 0; n < 4; ++n) {
      const int col = bn + wc + n * 16 + l15;
      const float bv = bias[col];
#pragma unroll
      for (int r = 0; r < 4; ++r) {
        const int row = bm + wr + m * 16 + l4 * 4 + r;
        C[(size_t)row * HH + col] = fmaf(acc[1][m][n][r], INVMID, acc[0][m][n][r]) + bv;
      }
    }
}

// fp32 currents -> f16 spikes, 4 elems/thread
__global__ __launch_bounds__(256)
void lif_scan_h4(const float4* __restrict__ cur, uint2* __restrict__ spk,
                 int NE4, int nt) {
  const int tid = blockIdx.x * 256 + threadIdx.x;
  float4 mem = make_float4(0.f, 0.f, 0.f, 0.f);
  auto step1 = [](float& m, float c) {
    const float reset = (m > 1.0f) ? 1.0f : 0.0f;
    m = __fsub_rn(__fadd_rn(__fmul_rn(0.9f, m), c), reset);
    return (m > 1.0f);
  };
#pragma unroll 4
  for (int t = 0; t < nt; ++t) {
    const float4 c = cur[(size_t)t * NE4 + tid];
    unsigned s0 = step1(mem.x, c.x) ? 0x3C00u : 0u;
    unsigned s1 = step1(mem.y, c.y) ? 0x3C00u : 0u;
    unsigned s2 = step1(mem.z, c.z) ? 0x3C00u : 0u;
    unsigned s3 = step1(mem.w, c.w) ? 0x3C00u : 0u;
    uint2 o;
    o.x = s0 | (s1 << 16);
    o.y = s2 | (s3 << 16);
    spk[(size_t)t * NE4 + tid] = o;
  }
}

// Fused layer-2 GEMM + LIF: ONE WAVE owns a 16b x 16d output tile for all T.
// No LDS, no barriers, no inter-wave coupling. W2 fragments (2 planes x 8
// k-chunks) in registers for the whole kernel; per t the wave loads its 8
// A-fragments from global (L2-resident t-slice; block's 4 waves share b-rows
// -> L1 reuse), runs 16 MFMAs, LIF in-register, stores spikes to d_out.
// A-regs double-buffered (aX/aY), t-loop unrolled x2 -> static reg indexing.
// MFMA chain order and LIF ops bitwise-identical to the unfused path.
__global__ __launch_bounds__(256)
void fused_l2(const unsigned short* __restrict__ spk1,   // [T][256][256] f16
              const unsigned short* __restrict__ W2s,    // 2 planes [784][256] f16
              const float* __restrict__ b2, float* __restrict__ out) {
  const int gw = (blockIdx.x << 2) | (threadIdx.x >> 6);  // 0..783
  const int lane = threadIdx.x & 63;
  const int l15 = lane & 15, l4 = lane >> 4;
  const int bb = gw / 49, dd = gw - bb * 49;   // 16 b-tiles x 49 d-tiles
  const int b0 = bb * 16, d0 = dd * 16;

  // W2 fragments: lane l15 -> d-row (d0+l15), l4 -> 16B k-chunk
  f16x8 wfr[2][8];
  const unsigned short* wbase = W2s + (size_t)(d0 + l15) * HH + l4 * 8;
#pragma unroll
  for (int s = 0; s < 2; ++s)
#pragma unroll
    for (int ks = 0; ks < 8; ++ks)
      wfr[s][ks] = *(const f16x8*)(wbase + (size_t)s * ((size_t)DD * HH) + ks * 32);
  const float bv = b2[d0 + l15];

  const unsigned short* abase = spk1 + (size_t)(b0 + l15) * HH + l4 * 8;
  float* obase = out + (size_t)(b0 + l4 * 4) * DD + d0 + l15;

  f32x4 mem = (f32x4){0.f, 0.f, 0.f, 0.f};
  f16x8 aX[8], aY[8];

#pragma unroll
  for (int ks = 0; ks < 8; ++ks)
    aX[ks] = *(const f16x8*)(abase + ks * 32);

  auto body = [&](int t, const f16x8 (&a)[8]) {
    f32x4 p0 = (f32x4){0.f, 0.f, 0.f, 0.f};
    f32x4 p1 = (f32x4){0.f, 0.f, 0.f, 0.f};
#pragma unroll
    for (int ks = 0; ks < 8; ++ks) {
      p0 = __builtin_amdgcn_mfma_f32_16x16x32_f16(a[ks], wfr[0][ks], p0, 0, 0, 0);
      p1 = __builtin_amdgcn_mfma_f32_16x16x32_f16(a[ks], wfr[1][ks], p1, 0, 0, 0);
    }
    float* op = obase + (size_t)t * ((size_t)BB * DD);
#pragma unroll
    for (int r = 0; r < 4; ++r) {
      const float cur = fmaf(p1[r], INVMID, p0[r]) + bv;
      const float reset = (mem[r] > 1.0f) ? 1.0f : 0.0f;
      mem[r] = __fsub_rn(__fadd_rn(__fmul_rn(0.9f, mem[r]), cur), reset);
      op[(size_t)r * DD] = (mem[r] > 1.0f) ? 1.0f : 0.0f;
    }
  };

  for (int t = 0; t < TT; t += 2) {
    const unsigned short* p1 = abase + (size_t)(t + 1) * (BB * HH);
#pragma unroll
    for (int ks = 0; ks < 8; ++ks)
      aY[ks] = *(const f16x8*)(p1 + ks * 32);
    body(t, aX);
    if (t + 2 < TT) {
      const unsigned short* p2 = abase + (size_t)(t + 2) * (BB * HH);
#pragma unroll
      for (int ks = 0; ks < 8; ++ks)
        aX[ks] = *(const f16x8*)(p2 + ks * 32);
    }
    body(t + 1, aY);
  }
}

extern "C" void kernel_launch(void* const* d_in, const int* in_sizes, int n_in,
                              void* d_out, int out_size, void* d_ws, size_t ws_size,
                              hipStream_t stream) {
  const float* x  = (const float*)d_in[0];
  const float* W1 = (const float*)d_in[1];
  const float* b1 = (const float*)d_in[2];
  const float* W2 = (const float*)d_in[3];
  const float* b2 = (const float*)d_in[4];
  float* out = (float*)d_out;

  const size_t w1s_elems = (size_t)2 * HH * K1PAD;   // 409600
  const size_t w2s_elems = (size_t)2 * DD * HH;      // 401408
  unsigned short* W1s = (unsigned short*)d_ws;
  unsigned short* W2s = W1s + w1s_elems;
  float* cur1 = (float*)(W2s + w2s_elems);
  unsigned short* spk1 = (unsigned short*)(cur1 + (size_t)MM * HH);

  dim3 blk(256);

  split_w<<<dim3((HH * K1PAD + 255) / 256), blk, 0, stream>>>(W1, W1s, HH, DD, HH, K1PAD);
  split_w<<<dim3((DD * HH + 255) / 256), blk, 0, stream>>>(W2, W2s, DD, HH, DD, HH);

  // layer 1: cur1[M,256] = X @ W1^T + b1 (fp32 binary A converted in staging)
  gemm1<<<dim3(MM / 128, HH / 128), blk, 0, stream>>>(x, W1s, b1, cur1);

  // layer 1 LIF -> f16 spikes
  lif_scan_h4<<<dim3((BB * HH / 4) / 256), blk, 0, stream>>>(
      (const float4*)cur1, (uint2*)spk1, BB * HH / 4, TT);

  // layer 2 GEMM + LIF fused, wave-autonomous, writes spikes directly to d_out
  fused_l2<<<dim3(16 * 49 / 4), blk, 0, stream>>>(spk1, W2s, b2, out);
}